// Round 17
// baseline (538.656 us; speedup 1.0000x reference)
//
#include <hip/hip_runtime.h>
#include <math.h>

#define T_TOKENS 16384
#define H_DIM 1024
#define F_DIM 2048
#define E_NUM 8
#define TPR 72                      // 256-row tiles per rank (16384/256 + 8 pad)
#define TOT_T (2 * TPR)             // 144
#define MAX_PAIRS (TOT_T * 256)     // 36864

typedef __attribute__((ext_vector_type(8))) short bf16x8;
typedef __attribute__((ext_vector_type(4))) float f32x4;
typedef __attribute__((ext_vector_type(4))) unsigned short us4;

struct TopK { int e0, e1; float w0, w1; };

__device__ __forceinline__ unsigned short f2bf(float f) {
  unsigned int u = __float_as_uint(f);
  u = (u + 0x7fffu + ((u >> 16) & 1u)) >> 16;
  return (unsigned short)u;
}

__device__ __forceinline__ float bf2f(unsigned short u) {
  return __uint_as_float(((unsigned int)u) << 16);
}

__device__ __forceinline__ void gload_lds16(const void* g, void* l) {
  __builtin_amdgcn_global_load_lds(
      (const __attribute__((address_space(1))) void*)g,
      (__attribute__((address_space(3))) void*)l, 16, 0, 0);
}

// ---------------- shared transpose body: in [E][R][C] f32 tile -> out [E][C][R] bf16
__device__ __forceinline__ void transpose_body(
    const float* __restrict__ in, unsigned short* __restrict__ out,
    int R, int C, int bx, int by, int e, float* tile /* [64][65] */) {
  int r0 = by * 64, c0 = bx * 64;
  int tid = threadIdx.x;
  const float* src = in + ((size_t)e * R + r0) * C + c0;
#pragma unroll
  for (int p = 0; p < 4; p++) {
    int id = p * 256 + tid;
    int row = id >> 4, c4 = (id & 15) * 4;
    float4 v = *(const float4*)&src[(size_t)row * C + c4];
    tile[row * 65 + c4 + 0] = v.x; tile[row * 65 + c4 + 1] = v.y;
    tile[row * 65 + c4 + 2] = v.z; tile[row * 65 + c4 + 3] = v.w;
  }
  __syncthreads();
  unsigned short* dst = out + ((size_t)e * C + c0) * R + r0;
#pragma unroll
  for (int p = 0; p < 4; p++) {
    int id = p * 256 + tid;
    int c = id >> 4, r4 = (id & 15) * 4;
    us4 pk;
#pragma unroll
    for (int j = 0; j < 4; j++) pk[j] = f2bf(tile[(r4 + j) * 65 + c]);
    *(us4*)&dst[(size_t)c * R + r4] = pk;
  }
}

// ---------------- fused prep: router (0..1023) + W1T (1024..5119) + W2T (5120..9215)
__global__ __launch_bounds__(256) void prep_kernel(
    const float* __restrict__ x, const float* __restrict__ Wg,
    const float* __restrict__ W1, const float* __restrict__ W2,
    unsigned short* __restrict__ xb, unsigned short* __restrict__ w1t,
    unsigned short* __restrict__ w2t, TopK* __restrict__ topk,
    int* __restrict__ counts, float* __restrict__ scal) {
  __shared__ __align__(16) char shraw[E_NUM * H_DIM * 4 + 256];
  int bid = blockIdx.x;
  int tid = threadIdx.x;
  if (bid >= 1024) {
    float* tile = (float*)shraw;
    if (bid < 5120) {
      int lb = bid - 1024;  // W1 [E][H][F] -> w1t [E][F][H]: R=H, C=F
      transpose_body(W1, w1t, H_DIM, F_DIM, lb & 31, (lb >> 5) & 15, lb >> 9, tile);
    } else {
      int lb = bid - 5120;  // W2 [E][F][H] -> w2t [E][H][F]: R=F, C=H
      transpose_body(W2, w2t, F_DIM, H_DIM, lb & 15, (lb >> 4) & 31, lb >> 9, tile);
    }
    return;
  }
  // -------- router role --------
  float (*wg)[H_DIM] = (float(*)[H_DIM])shraw;
  int* cnt = (int*)(shraw + E_NUM * H_DIM * 4);
  float (*sred)[5] = (float(*)[5])(shraw + E_NUM * H_DIM * 4 + 64);
  if (tid < 16) cnt[tid] = 0;
  for (int i = tid; i < E_NUM * H_DIM; i += 256) wg[i & 7][i >> 3] = Wg[i];
  __syncthreads();
  int lane = tid & 63, wid = tid >> 6;
  float zacc = 0.f, c0 = 0.f, c1 = 0.f, s0 = 0.f, s1 = 0.f;
  int wgid = bid * 4 + wid;
#pragma unroll
  for (int it = 0; it < 4; ++it) {
    int t = wgid + it * 4096;
    const float4* xr = (const float4*)(x + (size_t)t * H_DIM);
    us4* xbr = (us4*)(xb + (size_t)t * H_DIM);
    float l[E_NUM];
#pragma unroll
    for (int e = 0; e < E_NUM; e++) l[e] = 0.f;
#pragma unroll
    for (int i = 0; i < 4; i++) {
      int j = i * 64 + lane;
      float4 v = xr[j];
      us4 pk;
      pk[0] = f2bf(v.x); pk[1] = f2bf(v.y); pk[2] = f2bf(v.z); pk[3] = f2bf(v.w);
      xbr[j] = pk;
      int h = j * 4;
#pragma unroll
      for (int e = 0; e < E_NUM; e++) {
        const f32x4 wv = *(const f32x4*)&wg[e][h];
        l[e] = fmaf(v.x, wv[0], l[e]);
        l[e] = fmaf(v.y, wv[1], l[e]);
        l[e] = fmaf(v.z, wv[2], l[e]);
        l[e] = fmaf(v.w, wv[3], l[e]);
      }
    }
#pragma unroll
    for (int off = 32; off > 0; off >>= 1) {
#pragma unroll
      for (int e = 0; e < E_NUM; e++) l[e] += __shfl_xor(l[e], off, 64);
    }
    if (lane == 0) {
      float mx = l[0];
#pragma unroll
      for (int e = 1; e < E_NUM; e++) mx = fmaxf(mx, l[e]);
      float p[E_NUM]; float se = 0.f;
#pragma unroll
      for (int e = 0; e < E_NUM; e++) { p[e] = expf(l[e] - mx); se += p[e]; }
      float logz = logf(se) + mx;
      int e0 = 0; float b0 = p[0];
#pragma unroll
      for (int e = 1; e < E_NUM; e++) if (p[e] > b0) { b0 = p[e]; e0 = e; }
      int e1 = -1; float b1 = -1.f;
#pragma unroll
      for (int e = 0; e < E_NUM; e++) if (e != e0 && p[e] > b1) { b1 = p[e]; e1 = e; }
      float w0 = b0 / se, w1 = b1 / se;
      TopK tk; tk.e0 = e0; tk.e1 = e1; tk.w0 = w0; tk.w1 = w1;
      topk[t] = tk;
      atomicAdd(&cnt[e0], 1);
      atomicAdd(&cnt[8 + e1], 1);
      zacc += logz * logz;
      c0 += (e0 == 0 || e1 == 0) ? 1.f : 0.f;
      c1 += (e0 == 1 || e1 == 1) ? 1.f : 0.f;
      s0 += w0; s1 += w1;
    }
  }
  if (lane == 0) {
    sred[wid][0] = zacc; sred[wid][1] = c0; sred[wid][2] = c1;
    sred[wid][3] = s0;   sred[wid][4] = s1;
  }
  __syncthreads();
  if (tid == 0) {
    float a[5] = {0.f, 0.f, 0.f, 0.f, 0.f};
    for (int w2 = 0; w2 < 4; w2++)
      for (int k = 0; k < 5; k++) a[k] += sred[w2][k];
    for (int k = 0; k < 5; k++) atomicAdd(&scal[k], a[k]);
  }
  if (tid < 16 && cnt[tid]) atomicAdd(&counts[tid], cnt[tid]);
}

// ---------------- offsets padded to 256 rows per (rank, expert)
__global__ __launch_bounds__(256) void scan_kernel(
    const int* __restrict__ counts, int* __restrict__ po,
    int* __restrict__ tile_expert) {
  __shared__ int nt[16], start[16];
  int tid = threadIdx.x;
  if (tid < 16) {
    int r = tid >> 3, e = tid & 7;
    int s = 0;
    for (int j = 0; j < e; j++) s += (counts[(r << 3) + j] + 255) >> 8;
    nt[tid] = (counts[tid] + 255) >> 8;
    start[tid] = s;
    po[tid] = r * TPR * 256 + (s << 8);
  }
  __syncthreads();
  for (int ti = tid; ti < TOT_T; ti += 256) {
    int r = ti / TPR, local = ti % TPR;
    int ex = -1;
#pragma unroll
    for (int e = 0; e < E_NUM; e++) {
      int k = (r << 3) + e;
      if (local >= start[k] && local < start[k] + nt[k]) ex = e;
    }
    tile_expert[ti] = ex;
  }
}

// ---------------- assign with LDS-aggregated cursors (16 global atomics/block)
__global__ __launch_bounds__(256) void assign_kernel(
    const TopK* __restrict__ topk, const int* __restrict__ po,
    int* __restrict__ cursors, int* __restrict__ pair_token,
    float* __restrict__ pair_w, int* __restrict__ inv0, int* __restrict__ inv1) {
  __shared__ int lcnt[16], lbase[16];
  int tid = threadIdx.x;
  if (tid < 16) lcnt[tid] = 0;
  __syncthreads();
  int t = blockIdx.x * 256 + tid;
  TopK tk = topk[t];
  int li0 = atomicAdd(&lcnt[tk.e0], 1);
  int li1 = atomicAdd(&lcnt[8 + tk.e1], 1);
  __syncthreads();
  if (tid < 16) lbase[tid] = lcnt[tid] ? atomicAdd(&cursors[tid], lcnt[tid]) : 0;
  __syncthreads();
  int p0 = po[tk.e0] + lbase[tk.e0] + li0;
  pair_token[p0] = t; pair_w[p0] = tk.w0; inv0[t] = p0;
  int p1 = po[8 + tk.e1] + lbase[8 + tk.e1] + li1;
  pair_token[p1] = t; pair_w[p1] = tk.w1; inv1[t] = p1;
}

// ---------------- persistent grouped GEMM, 256x256 tile, 8 waves, R13 4-phase loop
// Grid = 256 (1 block/CU). Per-XCD ticket queue; ticket slot in dynamic LDS elem 0.
// Double barrier around the ticket read. (R15/R16's failure was NOT this design —
// it was tickets1 overlapping cursors[8..15] in the meta block; fixed in launch.)
// MODE 0: hmid[p,:] = gelu(xb[tok(p),:] @ W1t[e]^T)             (K=1024, N=2048)
// MODE 1: hmid[p,0:1024) = bf16( w(p) * (hmid[p,:] @ W2t[e]^T) ) in-place
template <int MODE, int K, int N, int NTILES>
__global__ __launch_bounds__(512) void moe_gemm8(
    const unsigned short* __restrict__ A, const unsigned short* __restrict__ Bt,
    const int* __restrict__ pair_token, const float* __restrict__ pair_w,
    const int* __restrict__ tile_expert, int* __restrict__ tickets,
    unsigned short* __restrict__ outbf) {
  constexpr int NBN = N / 256;
  constexpr int NTk = K / 64;
  constexpr int MTC = NTILES / 8;              // m-tiles per XCD
  constexpr int JOBS = NBN * MTC;              // jobs per XCD
  constexpr int OSTRIDE = (MODE == 0) ? N : K;
  int xcd = blockIdx.x & 7;                    // assumes HW xcd = blockIdx % 8

  extern __shared__ __align__(16) char smem_raw[];
  unsigned short* lds = (unsigned short*)smem_raw;   // 65536 elems = 128KB
  volatile int* ticket_slot = (volatile int*)lds;    // elem 0-1, rewritten per job

  int tid = threadIdx.x, lane = tid & 63, wid = tid >> 6;
  int wm = wid >> 2, wn = wid & 3;             // 2 x 4 wave grid, wave tile 128x64
  int lo = lane & 15, hi = lane >> 4;
  int l7 = lane & 7;

  int aRB = (wm * 64 + lo) * 64;               // + qa*8192 + mf*1024 + kd
  int bRB = (wn * 32 + lo) * 64;               // + 16384 + qb*8192 + nf*1024 + kd
  int kd0 = (hi ^ l7) * 8;                     // swizzled chunk, ks=0
  int kd1 = ((4 + hi) ^ l7) * 8;               // ks=1
  int kcs = ((tid & 7) ^ ((tid >> 3) & 7)) * 8;  // pre-swizzled source chunk
  int rr = tid >> 3;                             // 0..63

#define ST_A(qa, s, sb) do { if ((s) < NTk) { \
    gload_lds16(aSrc[qa][0] + (size_t)(s) * 64, lds + (sb) + (qa) * 8192 + wid * 512); \
    gload_lds16(aSrc[qa][1] + (size_t)(s) * 64, lds + (sb) + (qa) * 8192 + 4096 + wid * 512); } } while (0)
#define ST_B(qb, s, sb) do { if ((s) < NTk) { \
    gload_lds16(bSrc[qb][0] + (size_t)(s) * 64, lds + (sb) + 16384 + (qb) * 8192 + wid * 512); \
    gload_lds16(bSrc[qb][1] + (size_t)(s) * 64, lds + (sb) + 16384 + (qb) * 8192 + 4096 + wid * 512); } } while (0)
#define RD_A(dst, qa, rb) do { _Pragma("unroll") \
    for (int mf = 0; mf < 4; mf++) { \
      dst[mf * 2 + 0] = *(const bf16x8*)&lds[(rb) + (qa) * 8192 + aRB + mf * 1024 + kd0]; \
      dst[mf * 2 + 1] = *(const bf16x8*)&lds[(rb) + (qa) * 8192 + aRB + mf * 1024 + kd1]; } } while (0)
#define RD_B(dst, qb, rb) do { _Pragma("unroll") \
    for (int nf = 0; nf < 2; nf++) { \
      dst[nf * 2 + 0] = *(const bf16x8*)&lds[(rb) + 16384 + (qb) * 8192 + bRB + nf * 1024 + kd0]; \
      dst[nf * 2 + 1] = *(const bf16x8*)&lds[(rb) + 16384 + (qb) * 8192 + bRB + nf * 1024 + kd1]; } } while (0)
#define MMQ(aq, bq, QA, QB) do { __builtin_amdgcn_s_setprio(1); _Pragma("unroll") \
    for (int mf = 0; mf < 4; mf++) _Pragma("unroll") \
    for (int nf = 0; nf < 2; nf++) { \
      acc[(QA) * 4 + mf][(QB) * 2 + nf] = __builtin_amdgcn_mfma_f32_16x16x32_bf16( \
          bq[nf * 2 + 0], aq[mf * 2 + 0], acc[(QA) * 4 + mf][(QB) * 2 + nf], 0, 0, 0); \
      acc[(QA) * 4 + mf][(QB) * 2 + nf] = __builtin_amdgcn_mfma_f32_16x16x32_bf16( \
          bq[nf * 2 + 1], aq[mf * 2 + 1], acc[(QA) * 4 + mf][(QB) * 2 + nf], 0, 0, 0); } \
    __builtin_amdgcn_s_setprio(0); } while (0)
#define PH_BAR() do { asm volatile("s_barrier" ::: "memory"); \
    __builtin_amdgcn_sched_barrier(0); } while (0)
#define VMC(n) do { asm volatile("s_waitcnt vmcnt(" #n ")" ::: "memory"); \
    __builtin_amdgcn_sched_barrier(0); } while (0)

  for (;;) {
    if (tid == 0) *ticket_slot = atomicAdd(&tickets[xcd], 1);
    __syncthreads();                 // ticket write visible
    int job = *ticket_slot;
    __syncthreads();                 // all reads done before next write / staging
    if (job >= JOBS) break;
    int mt = xcd * MTC + job / NBN;
    int nb = job % NBN;
    int e = tile_expert[mt];
    if (e < 0) continue;             // padded tile (reads fenced above)
    int m0 = mt << 8, n0 = nb << 8;

    const unsigned short *aSrc[2][2], *bSrc[2][2];
#pragma unroll
    for (int qa = 0; qa < 2; qa++)
#pragma unroll
      for (int j = 0; j < 2; j++) {
        int row = j * 128 + qa * 64 + rr;
        size_t off;
        if (MODE == 0) {
          int tk = pair_token[m0 + row]; if (tk < 0) tk = 0;
          off = (size_t)tk * K;
        } else {
          off = (size_t)(m0 + row) * K;
        }
        aSrc[qa][j] = A + off + kcs;
      }
#pragma unroll
    for (int qb = 0; qb < 2; qb++)
#pragma unroll
      for (int j = 0; j < 2; j++) {
        int rp = j * 64 + rr;
        int col = (rp >> 5) * 64 + qb * 32 + (rp & 31);
        bSrc[qb][j] = Bt + ((size_t)e * N + n0 + col) * K + kcs;
      }

    f32x4 acc[8][4];
#pragma unroll
    for (int i = 0; i < 8; i++)
#pragma unroll
      for (int j = 0; j < 4; j++) acc[i][j] = (f32x4){0.f, 0.f, 0.f, 0.f};

    bf16x8 afr[8], bfr0[4], bfr1[4];

    // prologue: tile0 complete -> buf0; tile1 {A0,B0} -> buf1.
    ST_A(0, 0, 0); ST_B(0, 0, 0); ST_B(1, 0, 0); ST_A(1, 0, 0);
    ST_A(0, 1, 32768); ST_B(0, 1, 32768);
    VMC(4); PH_BAR();

    for (int t = 0; t < NTk; ++t) {
      int bo = (t & 1) << 15, bn = bo ^ 32768;
      // P1: read A0,B0(t); stage B1(t+1)->bn; vmcnt(8); bar; Q00
      RD_A(afr, 0, bo);
      RD_B(bfr0, 0, bo);
      ST_B(1, t + 1, bn);
      VMC(8); PH_BAR();
      MMQ(afr, bfr0, 0, 0);
      // P2: read B1(t); stage A1(t+1)->bn; bar; Q01
      RD_B(bfr1, 1, bo);
      ST_A(1, t + 1, bn);
      PH_BAR();
      MMQ(afr, bfr1, 0, 1);
      // P3: read A1(t); stage A0(t+2)->bo; vmcnt(8); bar; Q11
      RD_A(afr, 1, bo);
      ST_A(0, t + 2, bo);
      VMC(8); PH_BAR();
      MMQ(afr, bfr1, 1, 1);
      // P4: no reads; stage B0(t+2)->bo; bar; Q10 (regs only)
      ST_B(0, t + 2, bo);
      PH_BAR();
      MMQ(afr, bfr0, 1, 0);
    }
    // drain outstanding global_load_lds before epilogue / next job
    asm volatile("s_waitcnt vmcnt(0)" ::: "memory");
    __builtin_amdgcn_sched_barrier(0);

#pragma unroll
    for (int mh = 0; mh < 2; mh++)
#pragma unroll
      for (int mf = 0; mf < 4; mf++) {
        size_t p = m0 + wm * 128 + mh * 64 + mf * 16 + lo;
        float w = (MODE == 0) ? 0.f : pair_w[p];
#pragma unroll
        for (int nf = 0; nf < 4; nf++) {
          int f = n0 + wn * 64 + nf * 16 + hi * 4;
          us4 pk;
#pragma unroll
          for (int r = 0; r < 4; r++) {
            float v = acc[mh * 4 + mf][nf][r];
            if (MODE == 0) {
              float u = fmaf(0.044715f * v * v, v, v);
              float s = 1.f / (1.f + __expf(-1.5957691216057308f * u));
              pk[r] = f2bf(v * s);
            } else {
              pk[r] = f2bf(w * v);
            }
          }
          *(us4*)&outbf[p * (size_t)OSTRIDE + f] = pk;
        }
      }
  }
#undef ST_A
#undef ST_B
#undef RD_A
#undef RD_B
#undef MMQ
#undef PH_BAR
#undef VMC
}

// ---------------- combine (+ fused finalize in global idx 0)
__global__ __launch_bounds__(256) void combine_kernel(
    const unsigned short* __restrict__ hout, const int* __restrict__ inv0,
    const int* __restrict__ inv1, float* __restrict__ outp,
    const float* __restrict__ scal) {
  int idx = blockIdx.x * 256 + threadIdx.x;
  int t = idx >> 7;                  // 128 threads per token row
  int c = (idx & 127) * 8;
  int p0 = inv0[t], p1 = inv1[t];
  bf16x8 va = *(const bf16x8*)&hout[(size_t)p0 * F_DIM + c];
  bf16x8 vb = *(const bf16x8*)&hout[(size_t)p1 * F_DIM + c];
  float* orow = outp + (size_t)t * H_DIM + c;
  float4 o0, o1;
  o0.x = bf2f((unsigned short)va[0]) + bf2f((unsigned short)vb[0]);
  o0.y = bf2f((unsigned short)va[1]) + bf2f((unsigned short)vb[1]);
  o0.z = bf2f((unsigned short)va[2]) + bf2f((unsigned short)vb[2]);
  o0.w = bf2f((unsigned short)va[3]) + bf2f((unsigned short)vb[3]);
  o1.x = bf2f((unsigned short)va[4]) + bf2f((unsigned short)vb[4]);
  o1.y = bf2f((unsigned short)va[5]) + bf2f((unsigned short)vb[5]);
  o1.z = bf2f((unsigned short)va[6]) + bf2f((unsigned short)vb[6]);
  o1.w = bf2f((unsigned short)va[7]) + bf2f((unsigned short)vb[7]);
  *(float4*)&orow[0] = o0;
  *(float4*)&orow[4] = o1;
  if (idx == 0) {
    float invT = 1.f / (float)T_TOKENS;
    float* outTail = outp + (size_t)T_TOKENS * H_DIM;
    outTail[0] = scal[0] * invT;  // z_loss
    float tpe0 = scal[1] * invT, tpe1 = scal[2] * invT;
    float rp0 = scal[3] * invT, rp1 = scal[4] * invT;
    outTail[1] = (tpe0 * rp0 + tpe1 * rp1) * 0.5f * 4.f;  // aux (K=2 one_hot path)
  }
}

extern "C" void kernel_launch(void* const* d_in, const int* in_sizes, int n_in,
                              void* d_out, int out_size, void* d_ws, size_t ws_size,
                              hipStream_t stream) {
  const float* x  = (const float*)d_in[0];
  const float* Wg = (const float*)d_in[1];
  const float* W1 = (const float*)d_in[2];
  const float* W2 = (const float*)d_in[3];
  float* outp = (float*)d_out;

  char* w = (char*)d_ws;
  auto alloc = [&](size_t b) { char* p = w; w += (b + 511) & ~(size_t)511; return p; };
  // meta: scal @+0(32B), counts @+64(64B), cursors @+128(64B -> ends at +192),
  //       tickets1 @+192, tickets2 @+224.  (R15/R16 bug: tickets1 was at +160,
  //       INSIDE cursors[8..15] -> assign's cursor atomics pre-loaded the ticket
  //       queue past JOBS -> every GEMM block exited instantly -> zero output.)
  char*  meta        = alloc(256);
  float* scal        = (float*)(meta + 0);
  int*   counts      = (int*)(meta + 64);
  int*   cursors     = (int*)(meta + 128);
  int*   tickets1    = (int*)(meta + 192);
  int*   tickets2    = (int*)(meta + 224);
  int*   po          = (int*)alloc(64);
  int*   tile_expert = (int*)alloc(TOT_T * 4);
  TopK*  topk        = (TopK*)alloc((size_t)T_TOKENS * sizeof(TopK));
  int*   pair_token  = (int*)alloc((size_t)MAX_PAIRS * 4);
  float* pair_w      = (float*)alloc((size_t)MAX_PAIRS * 4);
  int*   inv0        = (int*)alloc((size_t)T_TOKENS * 4);
  int*   inv1        = (int*)alloc((size_t)T_TOKENS * 4);
  unsigned short* xb   = (unsigned short*)alloc((size_t)T_TOKENS * H_DIM * 2 + 512);
  unsigned short* w1t  = (unsigned short*)alloc((size_t)E_NUM * F_DIM * H_DIM * 2 + 512);
  unsigned short* hmid = (unsigned short*)alloc((size_t)MAX_PAIRS * F_DIM * 2 + 512);
  // w2t lives in d_out (64MB; w2t needs 32MB); combine overwrites d_out afterward.
  unsigned short* w2t = (unsigned short*)d_out;

  hipFuncSetAttribute((const void*)&moe_gemm8<0, H_DIM, F_DIM, TOT_T>,
                      hipFuncAttributeMaxDynamicSharedMemorySize, 131072);
  hipFuncSetAttribute((const void*)&moe_gemm8<1, F_DIM, H_DIM, TOT_T>,
                      hipFuncAttributeMaxDynamicSharedMemorySize, 131072);

  hipMemsetAsync(meta, 0, 256, stream);
  hipMemsetAsync(pair_token, 0xFF, (size_t)MAX_PAIRS * 4, stream);  // -1

  dim3 b256(256), b512(512);
  // fused prep: router (1024) + W1 transpose (4096) + W2 transpose (4096)
  prep_kernel<<<dim3(9216), b256, 0, stream>>>(x, Wg, W1, W2, xb, w1t, w2t,
                                               topk, counts, scal);
  scan_kernel<<<1, b256, 0, stream>>>(counts, po, tile_expert);
  assign_kernel<<<T_TOKENS / 256, b256, 0, stream>>>(topk, po, cursors, pair_token, pair_w,
                                                     inv0, inv1);
  // GEMM1 (persistent, 256 blocks): hmid = gelu(gather(xb) @ W1t^T)
  moe_gemm8<0, H_DIM, F_DIM, TOT_T><<<dim3(256), b512, 131072, stream>>>(
      xb, w1t, pair_token, pair_w, tile_expert, tickets1, hmid);
  // GEMM2 (persistent, 256 blocks): hmid[p][0:1024) = bf16(w(p)*(hmid[p]@W2t^T))
  moe_gemm8<1, F_DIM, H_DIM, TOT_T><<<dim3(256), b512, 131072, stream>>>(
      hmid, w2t, pair_token, pair_w, tile_expert, tickets2, hmid);
  // combine + fused finalize (overwrites all of d_out, incl. the w2t scratch)
  combine_kernel<<<dim3(T_TOKENS * 128 / 256), b256, 0, stream>>>(hmid, inv0, inv1, outp, scal);
}

// Round 18
// 472.141 us; speedup vs baseline: 1.1409x; 1.1409x over previous
//
#include <hip/hip_runtime.h>
#include <math.h>

#define T_TOKENS 16384
#define H_DIM 1024
#define F_DIM 2048
#define E_NUM 8
#define TPR 72                      // 256-row tiles per rank (16384/256 + 8 pad)
#define TOT_T (2 * TPR)             // 144
#define MAX_PAIRS (TOT_T * 256)     // 36864

typedef __attribute__((ext_vector_type(8))) short bf16x8;
typedef __attribute__((ext_vector_type(4))) float f32x4;
typedef __attribute__((ext_vector_type(4))) unsigned short us4;

struct TopK { int e0, e1; float w0, w1; };

__device__ __forceinline__ unsigned short f2bf(float f) {
  unsigned int u = __float_as_uint(f);
  u = (u + 0x7fffu + ((u >> 16) & 1u)) >> 16;
  return (unsigned short)u;
}

__device__ __forceinline__ float bf2f(unsigned short u) {
  return __uint_as_float(((unsigned int)u) << 16);
}

__device__ __forceinline__ void gload_lds16(const void* g, void* l) {
  __builtin_amdgcn_global_load_lds(
      (const __attribute__((address_space(1))) void*)g,
      (__attribute__((address_space(3))) void*)l, 16, 0, 0);
}

// ---------------- shared transpose body: in [E][R][C] f32 tile -> out [E][C][R] bf16
__device__ __forceinline__ void transpose_body(
    const float* __restrict__ in, unsigned short* __restrict__ out,
    int R, int C, int bx, int by, int e, float* tile /* [64][65] */) {
  int r0 = by * 64, c0 = bx * 64;
  int tid = threadIdx.x;
  const float* src = in + ((size_t)e * R + r0) * C + c0;
#pragma unroll
  for (int p = 0; p < 4; p++) {
    int id = p * 256 + tid;
    int row = id >> 4, c4 = (id & 15) * 4;
    float4 v = *(const float4*)&src[(size_t)row * C + c4];
    tile[row * 65 + c4 + 0] = v.x; tile[row * 65 + c4 + 1] = v.y;
    tile[row * 65 + c4 + 2] = v.z; tile[row * 65 + c4 + 3] = v.w;
  }
  __syncthreads();
  unsigned short* dst = out + ((size_t)e * C + c0) * R + r0;
#pragma unroll
  for (int p = 0; p < 4; p++) {
    int id = p * 256 + tid;
    int c = id >> 4, r4 = (id & 15) * 4;
    us4 pk;
#pragma unroll
    for (int j = 0; j < 4; j++) pk[j] = f2bf(tile[(r4 + j) * 65 + c]);
    *(us4*)&dst[(size_t)c * R + r4] = pk;
  }
}

// ---------------- fused prep: router (0..1023) + W1T (1024..5119) + W2T (5120..9215)
__global__ __launch_bounds__(256) void prep_kernel(
    const float* __restrict__ x, const float* __restrict__ Wg,
    const float* __restrict__ W1, const float* __restrict__ W2,
    unsigned short* __restrict__ xb, unsigned short* __restrict__ w1t,
    unsigned short* __restrict__ w2t, TopK* __restrict__ topk,
    int* __restrict__ counts, float* __restrict__ scal) {
  __shared__ __align__(16) char shraw[E_NUM * H_DIM * 4 + 256];
  int bid = blockIdx.x;
  int tid = threadIdx.x;
  if (bid >= 1024) {
    float* tile = (float*)shraw;
    if (bid < 5120) {
      int lb = bid - 1024;  // W1 [E][H][F] -> w1t [E][F][H]: R=H, C=F
      transpose_body(W1, w1t, H_DIM, F_DIM, lb & 31, (lb >> 5) & 15, lb >> 9, tile);
    } else {
      int lb = bid - 5120;  // W2 [E][F][H] -> w2t [E][H][F]: R=F, C=H
      transpose_body(W2, w2t, F_DIM, H_DIM, lb & 15, (lb >> 4) & 31, lb >> 9, tile);
    }
    return;
  }
  // -------- router role --------
  float (*wg)[H_DIM] = (float(*)[H_DIM])shraw;
  int* cnt = (int*)(shraw + E_NUM * H_DIM * 4);
  float (*sred)[5] = (float(*)[5])(shraw + E_NUM * H_DIM * 4 + 64);
  if (tid < 16) cnt[tid] = 0;
  for (int i = tid; i < E_NUM * H_DIM; i += 256) wg[i & 7][i >> 3] = Wg[i];
  __syncthreads();
  int lane = tid & 63, wid = tid >> 6;
  float zacc = 0.f, c0 = 0.f, c1 = 0.f, s0 = 0.f, s1 = 0.f;
  int wgid = bid * 4 + wid;
#pragma unroll
  for (int it = 0; it < 4; ++it) {
    int t = wgid + it * 4096;
    const float4* xr = (const float4*)(x + (size_t)t * H_DIM);
    us4* xbr = (us4*)(xb + (size_t)t * H_DIM);
    float l[E_NUM];
#pragma unroll
    for (int e = 0; e < E_NUM; e++) l[e] = 0.f;
#pragma unroll
    for (int i = 0; i < 4; i++) {
      int j = i * 64 + lane;
      float4 v = xr[j];
      us4 pk;
      pk[0] = f2bf(v.x); pk[1] = f2bf(v.y); pk[2] = f2bf(v.z); pk[3] = f2bf(v.w);
      xbr[j] = pk;
      int h = j * 4;
#pragma unroll
      for (int e = 0; e < E_NUM; e++) {
        const f32x4 wv = *(const f32x4*)&wg[e][h];
        l[e] = fmaf(v.x, wv[0], l[e]);
        l[e] = fmaf(v.y, wv[1], l[e]);
        l[e] = fmaf(v.z, wv[2], l[e]);
        l[e] = fmaf(v.w, wv[3], l[e]);
      }
    }
#pragma unroll
    for (int off = 32; off > 0; off >>= 1) {
#pragma unroll
      for (int e = 0; e < E_NUM; e++) l[e] += __shfl_xor(l[e], off, 64);
    }
    if (lane == 0) {
      float mx = l[0];
#pragma unroll
      for (int e = 1; e < E_NUM; e++) mx = fmaxf(mx, l[e]);
      float p[E_NUM]; float se = 0.f;
#pragma unroll
      for (int e = 0; e < E_NUM; e++) { p[e] = expf(l[e] - mx); se += p[e]; }
      float logz = logf(se) + mx;
      int e0 = 0; float b0 = p[0];
#pragma unroll
      for (int e = 1; e < E_NUM; e++) if (p[e] > b0) { b0 = p[e]; e0 = e; }
      int e1 = -1; float b1 = -1.f;
#pragma unroll
      for (int e = 0; e < E_NUM; e++) if (e != e0 && p[e] > b1) { b1 = p[e]; e1 = e; }
      float w0 = b0 / se, w1 = b1 / se;
      TopK tk; tk.e0 = e0; tk.e1 = e1; tk.w0 = w0; tk.w1 = w1;
      topk[t] = tk;
      atomicAdd(&cnt[e0], 1);
      atomicAdd(&cnt[8 + e1], 1);
      zacc += logz * logz;
      c0 += (e0 == 0 || e1 == 0) ? 1.f : 0.f;
      c1 += (e0 == 1 || e1 == 1) ? 1.f : 0.f;
      s0 += w0; s1 += w1;
    }
  }
  if (lane == 0) {
    sred[wid][0] = zacc; sred[wid][1] = c0; sred[wid][2] = c1;
    sred[wid][3] = s0;   sred[wid][4] = s1;
  }
  __syncthreads();
  if (tid == 0) {
    float a[5] = {0.f, 0.f, 0.f, 0.f, 0.f};
    for (int w2 = 0; w2 < 4; w2++)
      for (int k = 0; k < 5; k++) a[k] += sred[w2][k];
    for (int k = 0; k < 5; k++) atomicAdd(&scal[k], a[k]);
  }
  if (tid < 16 && cnt[tid]) atomicAdd(&counts[tid], cnt[tid]);
}

// ---------------- offsets padded to 256 rows per (rank, expert)
__global__ __launch_bounds__(256) void scan_kernel(
    const int* __restrict__ counts, int* __restrict__ po,
    int* __restrict__ tile_expert) {
  __shared__ int nt[16], start[16];
  int tid = threadIdx.x;
  if (tid < 16) {
    int r = tid >> 3, e = tid & 7;
    int s = 0;
    for (int j = 0; j < e; j++) s += (counts[(r << 3) + j] + 255) >> 8;
    nt[tid] = (counts[tid] + 255) >> 8;
    start[tid] = s;
    po[tid] = r * TPR * 256 + (s << 8);
  }
  __syncthreads();
  for (int ti = tid; ti < TOT_T; ti += 256) {
    int r = ti / TPR, local = ti % TPR;
    int ex = -1;
#pragma unroll
    for (int e = 0; e < E_NUM; e++) {
      int k = (r << 3) + e;
      if (local >= start[k] && local < start[k] + nt[k]) ex = e;
    }
    tile_expert[ti] = ex;
  }
}

// ---------------- assign with LDS-aggregated cursors (16 global atomics/block)
__global__ __launch_bounds__(256) void assign_kernel(
    const TopK* __restrict__ topk, const int* __restrict__ po,
    int* __restrict__ cursors, int* __restrict__ pair_token,
    float* __restrict__ pair_w, int* __restrict__ inv0, int* __restrict__ inv1) {
  __shared__ int lcnt[16], lbase[16];
  int tid = threadIdx.x;
  if (tid < 16) lcnt[tid] = 0;
  __syncthreads();
  int t = blockIdx.x * 256 + tid;
  TopK tk = topk[t];
  int li0 = atomicAdd(&lcnt[tk.e0], 1);
  int li1 = atomicAdd(&lcnt[8 + tk.e1], 1);
  __syncthreads();
  if (tid < 16) lbase[tid] = lcnt[tid] ? atomicAdd(&cursors[tid], lcnt[tid]) : 0;
  __syncthreads();
  int p0 = po[tk.e0] + lbase[tk.e0] + li0;
  pair_token[p0] = t; pair_w[p0] = tk.w0; inv0[t] = p0;
  int p1 = po[8 + tk.e1] + lbase[8 + tk.e1] + li1;
  pair_token[p1] = t; pair_w[p1] = tk.w1; inv1[t] = p1;
}

// ---------------- grouped GEMM, 256x256 tile, 8 waves, single-barrier 4-phase loop
// R13's proven body (188us, MfmaUtil 33%), static dispatch (persistent ticketing
// REVERTED: R17 measured +40us/GEMM and +40MB FETCH vs this).
// MODE 0: hmid[p,:] = gelu(xb[tok(p),:] @ W1t[e]^T)             (K=1024, N=2048)
// MODE 1: hmid[p,0:1024) = bf16( w(p) * (hmid[p,:] @ W2t[e]^T) ) in-place
template <int MODE, int K, int N, int NTILES>
__global__ __launch_bounds__(512) void moe_gemm8(
    const unsigned short* __restrict__ A, const unsigned short* __restrict__ Bt,
    const int* __restrict__ pair_token, const float* __restrict__ pair_w,
    const int* __restrict__ tile_expert, int tile_base,
    unsigned short* __restrict__ outbf) {
  constexpr int NBN = N / 256;
  constexpr int NTk = K / 64;
  constexpr int MTC = NTILES / 8;              // m-tiles per XCD
  constexpr int OSTRIDE = (MODE == 0) ? N : K; // output row stride (in-place for MODE 1)
  int l = blockIdx.x;
  int xcd = l & 7, idx = l >> 3;               // assumes HW xcd = blockIdx % 8
  int mt = tile_base + xcd * MTC + idx / NBN;  // m chunked per XCD
  int nb = idx % NBN;                          // n fast-varying among concurrent
  int e = tile_expert[mt];
  if (e < 0) return;
  int m0 = mt << 8, n0 = nb << 8;

  extern __shared__ __align__(16) char smem_raw[];
  unsigned short* lds = (unsigned short*)smem_raw;   // 65536 elems = 128KB

  int tid = threadIdx.x, lane = tid & 63, wid = tid >> 6;
  int wm = wid >> 2, wn = wid & 3;             // 2 x 4 wave grid, wave tile 128x64
  int lo = lane & 15, hi = lane >> 4;
  int l7 = lane & 7;

  int aRB = (wm * 64 + lo) * 64;               // + qa*8192 + mf*1024 + kd
  int bRB = (wn * 32 + lo) * 64;               // + 16384 + qb*8192 + nf*1024 + kd
  int kd0 = (hi ^ l7) * 8;                     // swizzled chunk, ks=0
  int kd1 = ((4 + hi) ^ l7) * 8;               // ks=1

  int kcs = ((tid & 7) ^ ((tid >> 3) & 7)) * 8;  // pre-swizzled source chunk (elems)
  int rr = tid >> 3;                             // 0..63
  const unsigned short *aSrc[2][2], *bSrc[2][2];
#pragma unroll
  for (int qa = 0; qa < 2; qa++)
#pragma unroll
    for (int j = 0; j < 2; j++) {
      int row = j * 128 + qa * 64 + rr;
      size_t off;
      if (MODE == 0) {
        int tk = pair_token[m0 + row]; if (tk < 0) tk = 0;
        off = (size_t)tk * K;
      } else {
        off = (size_t)(m0 + row) * K;
      }
      aSrc[qa][j] = A + off + kcs;
    }
#pragma unroll
  for (int qb = 0; qb < 2; qb++)
#pragma unroll
    for (int j = 0; j < 2; j++) {
      int rp = j * 64 + rr;
      int col = (rp >> 5) * 64 + qb * 32 + (rp & 31);
      bSrc[qb][j] = Bt + ((size_t)e * N + n0 + col) * K + kcs;
    }

#define ST_A(qa, s, sb) do { if ((s) < NTk) { \
    gload_lds16(aSrc[qa][0] + (size_t)(s) * 64, lds + (sb) + (qa) * 8192 + wid * 512); \
    gload_lds16(aSrc[qa][1] + (size_t)(s) * 64, lds + (sb) + (qa) * 8192 + 4096 + wid * 512); } } while (0)
#define ST_B(qb, s, sb) do { if ((s) < NTk) { \
    gload_lds16(bSrc[qb][0] + (size_t)(s) * 64, lds + (sb) + 16384 + (qb) * 8192 + wid * 512); \
    gload_lds16(bSrc[qb][1] + (size_t)(s) * 64, lds + (sb) + 16384 + (qb) * 8192 + 4096 + wid * 512); } } while (0)
#define RD_A(dst, qa, rb) do { _Pragma("unroll") \
    for (int mf = 0; mf < 4; mf++) { \
      dst[mf * 2 + 0] = *(const bf16x8*)&lds[(rb) + (qa) * 8192 + aRB + mf * 1024 + kd0]; \
      dst[mf * 2 + 1] = *(const bf16x8*)&lds[(rb) + (qa) * 8192 + aRB + mf * 1024 + kd1]; } } while (0)
#define RD_B(dst, qb, rb) do { _Pragma("unroll") \
    for (int nf = 0; nf < 2; nf++) { \
      dst[nf * 2 + 0] = *(const bf16x8*)&lds[(rb) + 16384 + (qb) * 8192 + bRB + nf * 1024 + kd0]; \
      dst[nf * 2 + 1] = *(const bf16x8*)&lds[(rb) + 16384 + (qb) * 8192 + bRB + nf * 1024 + kd1]; } } while (0)
#define MMQ(aq, bq, QA, QB) do { __builtin_amdgcn_s_setprio(1); _Pragma("unroll") \
    for (int mf = 0; mf < 4; mf++) _Pragma("unroll") \
    for (int nf = 0; nf < 2; nf++) { \
      acc[(QA) * 4 + mf][(QB) * 2 + nf] = __builtin_amdgcn_mfma_f32_16x16x32_bf16( \
          bq[nf * 2 + 0], aq[mf * 2 + 0], acc[(QA) * 4 + mf][(QB) * 2 + nf], 0, 0, 0); \
      acc[(QA) * 4 + mf][(QB) * 2 + nf] = __builtin_amdgcn_mfma_f32_16x16x32_bf16( \
          bq[nf * 2 + 1], aq[mf * 2 + 1], acc[(QA) * 4 + mf][(QB) * 2 + nf], 0, 0, 0); } \
    __builtin_amdgcn_s_setprio(0); } while (0)
#define PH_BAR() do { asm volatile("s_barrier" ::: "memory"); \
    __builtin_amdgcn_sched_barrier(0); } while (0)
#define VMC(n) do { asm volatile("s_waitcnt vmcnt(" #n ")" ::: "memory"); \
    __builtin_amdgcn_sched_barrier(0); } while (0)

  f32x4 acc[8][4];
#pragma unroll
  for (int i = 0; i < 8; i++)
#pragma unroll
    for (int j = 0; j < 4; j++) acc[i][j] = (f32x4){0.f, 0.f, 0.f, 0.f};

  bf16x8 afr[8], bfr0[4], bfr1[4];

  // prologue: tile0 complete -> buf0; tile1 {A0,B0} -> buf1.
  ST_A(0, 0, 0); ST_B(0, 0, 0); ST_B(1, 0, 0); ST_A(1, 0, 0);
  ST_A(0, 1, 32768); ST_B(0, 1, 32768);
  VMC(4); PH_BAR();

  for (int t = 0; t < NTk; ++t) {
    int bo = (t & 1) << 15, bn = bo ^ 32768;
    // P1: read A0,B0(t); stage B1(t+1)->bn; vmcnt(8); bar; Q00
    RD_A(afr, 0, bo);
    RD_B(bfr0, 0, bo);
    ST_B(1, t + 1, bn);
    VMC(8); PH_BAR();
    MMQ(afr, bfr0, 0, 0);
    // P2: read B1(t); stage A1(t+1)->bn; bar; Q01
    RD_B(bfr1, 1, bo);
    ST_A(1, t + 1, bn);
    PH_BAR();
    MMQ(afr, bfr1, 0, 1);
    // P3: read A1(t); stage A0(t+2)->bo; vmcnt(8); bar; Q11
    RD_A(afr, 1, bo);
    ST_A(0, t + 2, bo);
    VMC(8); PH_BAR();
    MMQ(afr, bfr1, 1, 1);
    // P4: no reads; stage B0(t+2)->bo; bar; Q10 (regs only)
    ST_B(0, t + 2, bo);
    PH_BAR();
    MMQ(afr, bfr0, 1, 0);
  }
  asm volatile("s_waitcnt vmcnt(0)" ::: "memory");
  __builtin_amdgcn_sched_barrier(0);
#undef ST_A
#undef ST_B
#undef RD_A
#undef RD_B
#undef MMQ
#undef PH_BAR
#undef VMC

#pragma unroll
  for (int mh = 0; mh < 2; mh++)
#pragma unroll
    for (int mf = 0; mf < 4; mf++) {
      size_t p = m0 + wm * 128 + mh * 64 + mf * 16 + lo;
      float w = (MODE == 0) ? 0.f : pair_w[p];
#pragma unroll
      for (int nf = 0; nf < 4; nf++) {
        int f = n0 + wn * 64 + nf * 16 + hi * 4;
        us4 pk;
#pragma unroll
        for (int r = 0; r < 4; r++) {
          float v = acc[mh * 4 + mf][nf][r];
          if (MODE == 0) {
            float u = fmaf(0.044715f * v * v, v, v);
            float s = 1.f / (1.f + __expf(-1.5957691216057308f * u));
            pk[r] = f2bf(v * s);
          } else {
            pk[r] = f2bf(w * v);
          }
        }
        *(us4*)&outbf[p * (size_t)OSTRIDE + f] = pk;
      }
    }
}

// ---------------- combine (+ fused finalize in global idx 0)
__global__ __launch_bounds__(256) void combine_kernel(
    const unsigned short* __restrict__ hout, const int* __restrict__ inv0,
    const int* __restrict__ inv1, float* __restrict__ outp,
    const float* __restrict__ scal) {
  int idx = blockIdx.x * 256 + threadIdx.x;
  int t = idx >> 7;                  // 128 threads per token row
  int c = (idx & 127) * 8;
  int p0 = inv0[t], p1 = inv1[t];
  bf16x8 va = *(const bf16x8*)&hout[(size_t)p0 * F_DIM + c];
  bf16x8 vb = *(const bf16x8*)&hout[(size_t)p1 * F_DIM + c];
  float* orow = outp + (size_t)t * H_DIM + c;
  float4 o0, o1;
  o0.x = bf2f((unsigned short)va[0]) + bf2f((unsigned short)vb[0]);
  o0.y = bf2f((unsigned short)va[1]) + bf2f((unsigned short)vb[1]);
  o0.z = bf2f((unsigned short)va[2]) + bf2f((unsigned short)vb[2]);
  o0.w = bf2f((unsigned short)va[3]) + bf2f((unsigned short)vb[3]);
  o1.x = bf2f((unsigned short)va[4]) + bf2f((unsigned short)vb[4]);
  o1.y = bf2f((unsigned short)va[5]) + bf2f((unsigned short)vb[5]);
  o1.z = bf2f((unsigned short)va[6]) + bf2f((unsigned short)vb[6]);
  o1.w = bf2f((unsigned short)va[7]) + bf2f((unsigned short)vb[7]);
  *(float4*)&orow[0] = o0;
  *(float4*)&orow[4] = o1;
  if (idx == 0) {
    float invT = 1.f / (float)T_TOKENS;
    float* outTail = outp + (size_t)T_TOKENS * H_DIM;
    outTail[0] = scal[0] * invT;  // z_loss
    float tpe0 = scal[1] * invT, tpe1 = scal[2] * invT;
    float rp0 = scal[3] * invT, rp1 = scal[4] * invT;
    outTail[1] = (tpe0 * rp0 + tpe1 * rp1) * 0.5f * 4.f;  // aux (K=2 one_hot path)
  }
}

extern "C" void kernel_launch(void* const* d_in, const int* in_sizes, int n_in,
                              void* d_out, int out_size, void* d_ws, size_t ws_size,
                              hipStream_t stream) {
  const float* x  = (const float*)d_in[0];
  const float* Wg = (const float*)d_in[1];
  const float* W1 = (const float*)d_in[2];
  const float* W2 = (const float*)d_in[3];
  float* outp = (float*)d_out;

  char* w = (char*)d_ws;
  auto alloc = [&](size_t b) { char* p = w; w += (b + 511) & ~(size_t)511; return p; };
  char*  meta        = alloc(256);
  float* scal        = (float*)(meta + 0);
  int*   counts      = (int*)(meta + 64);
  int*   cursors     = (int*)(meta + 128);
  int*   po          = (int*)alloc(64);
  int*   tile_expert = (int*)alloc(TOT_T * 4);
  TopK*  topk        = (TopK*)alloc((size_t)T_TOKENS * sizeof(TopK));
  int*   pair_token  = (int*)alloc((size_t)MAX_PAIRS * 4);
  float* pair_w      = (float*)alloc((size_t)MAX_PAIRS * 4);
  int*   inv0        = (int*)alloc((size_t)T_TOKENS * 4);
  int*   inv1        = (int*)alloc((size_t)T_TOKENS * 4);
  unsigned short* xb   = (unsigned short*)alloc((size_t)T_TOKENS * H_DIM * 2 + 512);
  unsigned short* w1t  = (unsigned short*)alloc((size_t)E_NUM * F_DIM * H_DIM * 2 + 512);
  unsigned short* hmid = (unsigned short*)alloc((size_t)MAX_PAIRS * F_DIM * 2 + 512);
  // w2t lives in d_out (64MB; w2t needs 32MB); combine overwrites d_out afterward.
  unsigned short* w2t = (unsigned short*)d_out;

  hipFuncSetAttribute((const void*)&moe_gemm8<0, H_DIM, F_DIM, TOT_T>,
                      hipFuncAttributeMaxDynamicSharedMemorySize, 131072);
  hipFuncSetAttribute((const void*)&moe_gemm8<1, F_DIM, H_DIM, TOT_T>,
                      hipFuncAttributeMaxDynamicSharedMemorySize, 131072);

  hipMemsetAsync(meta, 0, 256, stream);
  hipMemsetAsync(pair_token, 0xFF, (size_t)MAX_PAIRS * 4, stream);  // -1

  dim3 b256(256), b512(512);
  // fused prep: router (1024) + W1 transpose (4096) + W2 transpose (4096)
  prep_kernel<<<dim3(9216), b256, 0, stream>>>(x, Wg, W1, W2, xb, w1t, w2t,
                                               topk, counts, scal);
  scan_kernel<<<1, b256, 0, stream>>>(counts, po, tile_expert);
  assign_kernel<<<T_TOKENS / 256, b256, 0, stream>>>(topk, po, cursors, pair_token, pair_w,
                                                     inv0, inv1);
  // GEMM1 (static, 1152 blocks): hmid = gelu(gather(xb) @ W1t^T)
  moe_gemm8<0, H_DIM, F_DIM, TOT_T><<<dim3((F_DIM / 256) * TOT_T), b512, 131072, stream>>>(
      xb, w1t, pair_token, pair_w, tile_expert, 0, hmid);
  // GEMM2 (static, 576 blocks): hmid[p][0:1024) = bf16(w(p)*(hmid[p]@W2t^T)) in-place
  moe_gemm8<1, F_DIM, H_DIM, TOT_T><<<dim3((H_DIM / 256) * TOT_T), b512, 131072, stream>>>(
      hmid, w2t, pair_token, pair_w, tile_expert, 0, hmid);
  // combine + fused finalize (overwrites all of d_out, incl. the w2t scratch)
  combine_kernel<<<dim3(T_TOKENS * 128 / 256), b256, 0, stream>>>(hmid, inv0, inv1, outp, scal);
}

// Round 20
// 472.067 us; speedup vs baseline: 1.1411x; 1.0002x over previous
//
#include <hip/hip_runtime.h>
#include <math.h>

#define T_TOKENS 16384
#define H_DIM 1024
#define F_DIM 2048
#define E_NUM 8
#define TPR 72                      // 256-row tiles per rank (16384/256 + 8 pad)
#define TOT_T (2 * TPR)             // 144
#define MAX_PAIRS (TOT_T * 256)     // 36864

typedef __attribute__((ext_vector_type(8))) short bf16x8;
typedef __attribute__((ext_vector_type(4))) float f32x4;
typedef __attribute__((ext_vector_type(4))) unsigned short us4;

struct TopK { int e0, e1; float w0, w1; };

__device__ __forceinline__ unsigned short f2bf(float f) {
  unsigned int u = __float_as_uint(f);
  u = (u + 0x7fffu + ((u >> 16) & 1u)) >> 16;
  return (unsigned short)u;
}

__device__ __forceinline__ float bf2f(unsigned short u) {
  return __uint_as_float(((unsigned int)u) << 16);
}

__device__ __forceinline__ void gload_lds16(const void* g, void* l) {
  __builtin_amdgcn_global_load_lds(
      (const __attribute__((address_space(1))) void*)g,
      (__attribute__((address_space(3))) void*)l, 16, 0, 0);
}

// ---------------- shared transpose body: in [E][R][C] f32 tile -> out [E][C][R] bf16
__device__ __forceinline__ void transpose_body(
    const float* __restrict__ in, unsigned short* __restrict__ out,
    int R, int C, int bx, int by, int e, float* tile /* [64][65] */) {
  int r0 = by * 64, c0 = bx * 64;
  int tid = threadIdx.x;
  const float* src = in + ((size_t)e * R + r0) * C + c0;
#pragma unroll
  for (int p = 0; p < 4; p++) {
    int id = p * 256 + tid;
    int row = id >> 4, c4 = (id & 15) * 4;
    float4 v = *(const float4*)&src[(size_t)row * C + c4];
    tile[row * 65 + c4 + 0] = v.x; tile[row * 65 + c4 + 1] = v.y;
    tile[row * 65 + c4 + 2] = v.z; tile[row * 65 + c4 + 3] = v.w;
  }
  __syncthreads();
  unsigned short* dst = out + ((size_t)e * C + c0) * R + r0;
#pragma unroll
  for (int p = 0; p < 4; p++) {
    int id = p * 256 + tid;
    int c = id >> 4, r4 = (id & 15) * 4;
    us4 pk;
#pragma unroll
    for (int j = 0; j < 4; j++) pk[j] = f2bf(tile[(r4 + j) * 65 + c]);
    *(us4*)&dst[(size_t)c * R + r4] = pk;
  }
}

// ---------------- fused prep: router (0..1023) + W1T (1024..5119) + W2T (5120..9215)
__global__ __launch_bounds__(256) void prep_kernel(
    const float* __restrict__ x, const float* __restrict__ Wg,
    const float* __restrict__ W1, const float* __restrict__ W2,
    unsigned short* __restrict__ xb, unsigned short* __restrict__ w1t,
    unsigned short* __restrict__ w2t, TopK* __restrict__ topk,
    int* __restrict__ counts, float* __restrict__ scal) {
  __shared__ __align__(16) char shraw[E_NUM * H_DIM * 4 + 256];
  int bid = blockIdx.x;
  int tid = threadIdx.x;
  if (bid >= 1024) {
    float* tile = (float*)shraw;
    if (bid < 5120) {
      int lb = bid - 1024;  // W1 [E][H][F] -> w1t [E][F][H]: R=H, C=F
      transpose_body(W1, w1t, H_DIM, F_DIM, lb & 31, (lb >> 5) & 15, lb >> 9, tile);
    } else {
      int lb = bid - 5120;  // W2 [E][F][H] -> w2t [E][H][F]: R=F, C=H
      transpose_body(W2, w2t, F_DIM, H_DIM, lb & 15, (lb >> 4) & 31, lb >> 9, tile);
    }
    return;
  }
  // -------- router role --------
  float (*wg)[H_DIM] = (float(*)[H_DIM])shraw;
  int* cnt = (int*)(shraw + E_NUM * H_DIM * 4);
  float (*sred)[5] = (float(*)[5])(shraw + E_NUM * H_DIM * 4 + 64);
  if (tid < 16) cnt[tid] = 0;
  for (int i = tid; i < E_NUM * H_DIM; i += 256) wg[i & 7][i >> 3] = Wg[i];
  __syncthreads();
  int lane = tid & 63, wid = tid >> 6;
  float zacc = 0.f, c0 = 0.f, c1 = 0.f, s0 = 0.f, s1 = 0.f;
  int wgid = bid * 4 + wid;
#pragma unroll
  for (int it = 0; it < 4; ++it) {
    int t = wgid + it * 4096;
    const float4* xr = (const float4*)(x + (size_t)t * H_DIM);
    us4* xbr = (us4*)(xb + (size_t)t * H_DIM);
    float l[E_NUM];
#pragma unroll
    for (int e = 0; e < E_NUM; e++) l[e] = 0.f;
#pragma unroll
    for (int i = 0; i < 4; i++) {
      int j = i * 64 + lane;
      float4 v = xr[j];
      us4 pk;
      pk[0] = f2bf(v.x); pk[1] = f2bf(v.y); pk[2] = f2bf(v.z); pk[3] = f2bf(v.w);
      xbr[j] = pk;
      int h = j * 4;
#pragma unroll
      for (int e = 0; e < E_NUM; e++) {
        const f32x4 wv = *(const f32x4*)&wg[e][h];
        l[e] = fmaf(v.x, wv[0], l[e]);
        l[e] = fmaf(v.y, wv[1], l[e]);
        l[e] = fmaf(v.z, wv[2], l[e]);
        l[e] = fmaf(v.w, wv[3], l[e]);
      }
    }
#pragma unroll
    for (int off = 32; off > 0; off >>= 1) {
#pragma unroll
      for (int e = 0; e < E_NUM; e++) l[e] += __shfl_xor(l[e], off, 64);
    }
    if (lane == 0) {
      float mx = l[0];
#pragma unroll
      for (int e = 1; e < E_NUM; e++) mx = fmaxf(mx, l[e]);
      float p[E_NUM]; float se = 0.f;
#pragma unroll
      for (int e = 0; e < E_NUM; e++) { p[e] = expf(l[e] - mx); se += p[e]; }
      float logz = logf(se) + mx;
      int e0 = 0; float b0 = p[0];
#pragma unroll
      for (int e = 1; e < E_NUM; e++) if (p[e] > b0) { b0 = p[e]; e0 = e; }
      int e1 = -1; float b1 = -1.f;
#pragma unroll
      for (int e = 0; e < E_NUM; e++) if (e != e0 && p[e] > b1) { b1 = p[e]; e1 = e; }
      float w0 = b0 / se, w1 = b1 / se;
      TopK tk; tk.e0 = e0; tk.e1 = e1; tk.w0 = w0; tk.w1 = w1;
      topk[t] = tk;
      atomicAdd(&cnt[e0], 1);
      atomicAdd(&cnt[8 + e1], 1);
      zacc += logz * logz;
      c0 += (e0 == 0 || e1 == 0) ? 1.f : 0.f;
      c1 += (e0 == 1 || e1 == 1) ? 1.f : 0.f;
      s0 += w0; s1 += w1;
    }
  }
  if (lane == 0) {
    sred[wid][0] = zacc; sred[wid][1] = c0; sred[wid][2] = c1;
    sred[wid][3] = s0;   sred[wid][4] = s1;
  }
  __syncthreads();
  if (tid == 0) {
    float a[5] = {0.f, 0.f, 0.f, 0.f, 0.f};
    for (int w2 = 0; w2 < 4; w2++)
      for (int k = 0; k < 5; k++) a[k] += sred[w2][k];
    for (int k = 0; k < 5; k++) atomicAdd(&scal[k], a[k]);
  }
  if (tid < 16 && cnt[tid]) atomicAdd(&counts[tid], cnt[tid]);
}

// ---------------- offsets padded to 256 rows per (rank, expert)
__global__ __launch_bounds__(256) void scan_kernel(
    const int* __restrict__ counts, int* __restrict__ po,
    int* __restrict__ tile_expert) {
  __shared__ int nt[16], start[16];
  int tid = threadIdx.x;
  if (tid < 16) {
    int r = tid >> 3, e = tid & 7;
    int s = 0;
    for (int j = 0; j < e; j++) s += (counts[(r << 3) + j] + 255) >> 8;
    nt[tid] = (counts[tid] + 255) >> 8;
    start[tid] = s;
    po[tid] = r * TPR * 256 + (s << 8);
  }
  __syncthreads();
  for (int ti = tid; ti < TOT_T; ti += 256) {
    int r = ti / TPR, local = ti % TPR;
    int ex = -1;
#pragma unroll
    for (int e = 0; e < E_NUM; e++) {
      int k = (r << 3) + e;
      if (local >= start[k] && local < start[k] + nt[k]) ex = e;
    }
    tile_expert[ti] = ex;
  }
}

// ---------------- assign with LDS-aggregated cursors (16 global atomics/block)
__global__ __launch_bounds__(256) void assign_kernel(
    const TopK* __restrict__ topk, const int* __restrict__ po,
    int* __restrict__ cursors, int* __restrict__ pair_token,
    float* __restrict__ pair_w, int* __restrict__ inv0, int* __restrict__ inv1) {
  __shared__ int lcnt[16], lbase[16];
  int tid = threadIdx.x;
  if (tid < 16) lcnt[tid] = 0;
  __syncthreads();
  int t = blockIdx.x * 256 + tid;
  TopK tk = topk[t];
  int li0 = atomicAdd(&lcnt[tk.e0], 1);
  int li1 = atomicAdd(&lcnt[8 + tk.e1], 1);
  __syncthreads();
  if (tid < 16) lbase[tid] = lcnt[tid] ? atomicAdd(&cursors[tid], lcnt[tid]) : 0;
  __syncthreads();
  int p0 = po[tk.e0] + lbase[tk.e0] + li0;
  pair_token[p0] = t; pair_w[p0] = tk.w0; inv0[t] = p0;
  int p1 = po[8 + tk.e1] + lbase[8 + tk.e1] + li1;
  pair_token[p1] = t; pair_w[p1] = tk.w1; inv1[t] = p1;
}

// ---------------- grouped GEMM, 256x256 tile, 8 waves, single-barrier 4-phase loop
// R13's proven body (188-192us, MfmaUtil 33%), static dispatch.
// MODE 0: hmid[p,:] = gelu(xb[tok(p),:] @ W1t[e]^T)             (K=1024, N=2048)
// MODE 1: hmid[p,0:1024) = bf16( w(p) * (hmid[p,:] @ W2t[e]^T) ) in-place
template <int MODE, int K, int N, int NTILES>
__global__ __launch_bounds__(512) void moe_gemm8(
    const unsigned short* __restrict__ A, const unsigned short* __restrict__ Bt,
    const int* __restrict__ pair_token, const float* __restrict__ pair_w,
    const int* __restrict__ tile_expert, int tile_base,
    unsigned short* __restrict__ outbf) {
  constexpr int NBN = N / 256;
  constexpr int NTk = K / 64;
  constexpr int MTC = NTILES / 8;              // m-tiles per XCD
  constexpr int OSTRIDE = (MODE == 0) ? N : K; // output row stride (in-place for MODE 1)
  int l = blockIdx.x;
  int xcd = l & 7, idx = l >> 3;               // assumes HW xcd = blockIdx % 8
  int mt = tile_base + xcd * MTC + idx / NBN;  // m chunked per XCD
  int nb = idx % NBN;                          // n fast-varying among concurrent
  int e = tile_expert[mt];
  if (e < 0) return;
  int m0 = mt << 8, n0 = nb << 8;

  extern __shared__ __align__(16) char smem_raw[];
  unsigned short* lds = (unsigned short*)smem_raw;   // 65536 elems = 128KB

  int tid = threadIdx.x, lane = tid & 63, wid = tid >> 6;
  int wm = wid >> 2, wn = wid & 3;             // 2 x 4 wave grid, wave tile 128x64
  int lo = lane & 15, hi = lane >> 4;
  int l7 = lane & 7;

  int aRB = (wm * 64 + lo) * 64;               // + qa*8192 + mf*1024 + kd
  int bRB = (wn * 32 + lo) * 64;               // + 16384 + qb*8192 + nf*1024 + kd
  int kd0 = (hi ^ l7) * 8;                     // swizzled chunk, ks=0
  int kd1 = ((4 + hi) ^ l7) * 8;               // ks=1

  int kcs = ((tid & 7) ^ ((tid >> 3) & 7)) * 8;  // pre-swizzled source chunk (elems)
  int rr = tid >> 3;                             // 0..63
  const unsigned short *aSrc[2][2], *bSrc[2][2];
#pragma unroll
  for (int qa = 0; qa < 2; qa++)
#pragma unroll
    for (int j = 0; j < 2; j++) {
      int row = j * 128 + qa * 64 + rr;
      size_t off;
      if (MODE == 0) {
        int tk = pair_token[m0 + row]; if (tk < 0) tk = 0;
        off = (size_t)tk * K;
      } else {
        off = (size_t)(m0 + row) * K;
      }
      aSrc[qa][j] = A + off + kcs;
    }
#pragma unroll
  for (int qb = 0; qb < 2; qb++)
#pragma unroll
    for (int j = 0; j < 2; j++) {
      int rp = j * 64 + rr;
      int col = (rp >> 5) * 64 + qb * 32 + (rp & 31);
      bSrc[qb][j] = Bt + ((size_t)e * N + n0 + col) * K + kcs;
    }

#define ST_A(qa, s, sb) do { if ((s) < NTk) { \
    gload_lds16(aSrc[qa][0] + (size_t)(s) * 64, lds + (sb) + (qa) * 8192 + wid * 512); \
    gload_lds16(aSrc[qa][1] + (size_t)(s) * 64, lds + (sb) + (qa) * 8192 + 4096 + wid * 512); } } while (0)
#define ST_B(qb, s, sb) do { if ((s) < NTk) { \
    gload_lds16(bSrc[qb][0] + (size_t)(s) * 64, lds + (sb) + 16384 + (qb) * 8192 + wid * 512); \
    gload_lds16(bSrc[qb][1] + (size_t)(s) * 64, lds + (sb) + 16384 + (qb) * 8192 + 4096 + wid * 512); } } while (0)
#define RD_A(dst, qa, rb) do { _Pragma("unroll") \
    for (int mf = 0; mf < 4; mf++) { \
      dst[mf * 2 + 0] = *(const bf16x8*)&lds[(rb) + (qa) * 8192 + aRB + mf * 1024 + kd0]; \
      dst[mf * 2 + 1] = *(const bf16x8*)&lds[(rb) + (qa) * 8192 + aRB + mf * 1024 + kd1]; } } while (0)
#define RD_B(dst, qb, rb) do { _Pragma("unroll") \
    for (int nf = 0; nf < 2; nf++) { \
      dst[nf * 2 + 0] = *(const bf16x8*)&lds[(rb) + 16384 + (qb) * 8192 + bRB + nf * 1024 + kd0]; \
      dst[nf * 2 + 1] = *(const bf16x8*)&lds[(rb) + 16384 + (qb) * 8192 + bRB + nf * 1024 + kd1]; } } while (0)
#define MMQ(aq, bq, QA, QB) do { __builtin_amdgcn_s_setprio(1); _Pragma("unroll") \
    for (int mf = 0; mf < 4; mf++) _Pragma("unroll") \
    for (int nf = 0; nf < 2; nf++) { \
      acc[(QA) * 4 + mf][(QB) * 2 + nf] = __builtin_amdgcn_mfma_f32_16x16x32_bf16( \
          bq[nf * 2 + 0], aq[mf * 2 + 0], acc[(QA) * 4 + mf][(QB) * 2 + nf], 0, 0, 0); \
      acc[(QA) * 4 + mf][(QB) * 2 + nf] = __builtin_amdgcn_mfma_f32_16x16x32_bf16( \
          bq[nf * 2 + 1], aq[mf * 2 + 1], acc[(QA) * 4 + mf][(QB) * 2 + nf], 0, 0, 0); } \
    __builtin_amdgcn_s_setprio(0); } while (0)
#define PH_BAR() do { asm volatile("s_barrier" ::: "memory"); \
    __builtin_amdgcn_sched_barrier(0); } while (0)
#define VMC(n) do { asm volatile("s_waitcnt vmcnt(" #n ")" ::: "memory"); \
    __builtin_amdgcn_sched_barrier(0); } while (0)

  f32x4 acc[8][4];
#pragma unroll
  for (int i = 0; i < 8; i++)
#pragma unroll
    for (int j = 0; j < 4; j++) acc[i][j] = (f32x4){0.f, 0.f, 0.f, 0.f};

  bf16x8 afr[8], bfr0[4], bfr1[4];

  // prologue: tile0 complete -> buf0; tile1 {A0,B0} -> buf1.
  ST_A(0, 0, 0); ST_B(0, 0, 0); ST_B(1, 0, 0); ST_A(1, 0, 0);
  ST_A(0, 1, 32768); ST_B(0, 1, 32768);
  VMC(4); PH_BAR();

  for (int t = 0; t < NTk; ++t) {
    int bo = (t & 1) << 15, bn = bo ^ 32768;
    // P1: read A0,B0(t); stage B1(t+1)->bn; vmcnt(8); bar; Q00
    RD_A(afr, 0, bo);
    RD_B(bfr0, 0, bo);
    ST_B(1, t + 1, bn);
    VMC(8); PH_BAR();
    MMQ(afr, bfr0, 0, 0);
    // P2: read B1(t); stage A1(t+1)->bn; bar; Q01
    RD_B(bfr1, 1, bo);
    ST_A(1, t + 1, bn);
    PH_BAR();
    MMQ(afr, bfr1, 0, 1);
    // P3: read A1(t); stage A0(t+2)->bo; vmcnt(8); bar; Q11
    RD_A(afr, 1, bo);
    ST_A(0, t + 2, bo);
    VMC(8); PH_BAR();
    MMQ(afr, bfr1, 1, 1);
    // P4: no reads; stage B0(t+2)->bo; bar; Q10 (regs only)
    ST_B(0, t + 2, bo);
    PH_BAR();
    MMQ(afr, bfr0, 1, 0);
  }
  asm volatile("s_waitcnt vmcnt(0)" ::: "memory");
  __builtin_amdgcn_sched_barrier(0);
#undef ST_A
#undef ST_B
#undef RD_A
#undef RD_B
#undef MMQ
#undef PH_BAR
#undef VMC

#pragma unroll
  for (int mh = 0; mh < 2; mh++)
#pragma unroll
    for (int mf = 0; mf < 4; mf++) {
      size_t p = m0 + wm * 128 + mh * 64 + mf * 16 + lo;
      float w = (MODE == 0) ? 0.f : pair_w[p];
#pragma unroll
      for (int nf = 0; nf < 4; nf++) {
        int f = n0 + wn * 64 + nf * 16 + hi * 4;
        us4 pk;
#pragma unroll
        for (int r = 0; r < 4; r++) {
          float v = acc[mh * 4 + mf][nf][r];
          if (MODE == 0) {
            float u = fmaf(0.044715f * v * v, v, v);
            float s = 1.f / (1.f + __expf(-1.5957691216057308f * u));
            pk[r] = f2bf(v * s);
          } else {
            pk[r] = f2bf(w * v);
          }
        }
        *(us4*)&outbf[p * (size_t)OSTRIDE + f] = pk;
      }
    }
}

// ---------------- combine (+ fused finalize in global idx 0)
__global__ __launch_bounds__(256) void combine_kernel(
    const unsigned short* __restrict__ hout, const int* __restrict__ inv0,
    const int* __restrict__ inv1, float* __restrict__ outp,
    const float* __restrict__ scal) {
  int idx = blockIdx.x * 256 + threadIdx.x;
  int t = idx >> 7;                  // 128 threads per token row
  int c = (idx & 127) * 8;
  int p0 = inv0[t], p1 = inv1[t];
  bf16x8 va = *(const bf16x8*)&hout[(size_t)p0 * F_DIM + c];
  bf16x8 vb = *(const bf16x8*)&hout[(size_t)p1 * F_DIM + c];
  float* orow = outp + (size_t)t * H_DIM + c;
  float4 o0, o1;
  o0.x = bf2f((unsigned short)va[0]) + bf2f((unsigned short)vb[0]);
  o0.y = bf2f((unsigned short)va[1]) + bf2f((unsigned short)vb[1]);
  o0.z = bf2f((unsigned short)va[2]) + bf2f((unsigned short)vb[2]);
  o0.w = bf2f((unsigned short)va[3]) + bf2f((unsigned short)vb[3]);
  o1.x = bf2f((unsigned short)va[4]) + bf2f((unsigned short)vb[4]);
  o1.y = bf2f((unsigned short)va[5]) + bf2f((unsigned short)vb[5]);
  o1.z = bf2f((unsigned short)va[6]) + bf2f((unsigned short)vb[6]);
  o1.w = bf2f((unsigned short)va[7]) + bf2f((unsigned short)vb[7]);
  *(float4*)&orow[0] = o0;
  *(float4*)&orow[4] = o1;
  if (idx == 0) {
    float invT = 1.f / (float)T_TOKENS;
    float* outTail = outp + (size_t)T_TOKENS * H_DIM;
    outTail[0] = scal[0] * invT;  // z_loss
    float tpe0 = scal[1] * invT, tpe1 = scal[2] * invT;
    float rp0 = scal[3] * invT, rp1 = scal[4] * invT;
    outTail[1] = (tpe0 * rp0 + tpe1 * rp1) * 0.5f * 4.f;  // aux (K=2 one_hot path)
  }
}

extern "C" void kernel_launch(void* const* d_in, const int* in_sizes, int n_in,
                              void* d_out, int out_size, void* d_ws, size_t ws_size,
                              hipStream_t stream) {
  const float* x  = (const float*)d_in[0];
  const float* Wg = (const float*)d_in[1];
  const float* W1 = (const float*)d_in[2];
  const float* W2 = (const float*)d_in[3];
  float* outp = (float*)d_out;

  char* w = (char*)d_ws;
  auto alloc = [&](size_t b) { char* p = w; w += (b + 511) & ~(size_t)511; return p; };
  char*  meta        = alloc(256);
  float* scal        = (float*)(meta + 0);
  int*   counts      = (int*)(meta + 64);
  int*   cursors     = (int*)(meta + 128);
  int*   po          = (int*)alloc(64);
  int*   tile_expert = (int*)alloc(TOT_T * 4);
  TopK*  topk        = (TopK*)alloc((size_t)T_TOKENS * sizeof(TopK));
  int*   pair_token  = (int*)alloc((size_t)MAX_PAIRS * 4);
  float* pair_w      = (float*)alloc((size_t)MAX_PAIRS * 4);
  int*   inv0        = (int*)alloc((size_t)T_TOKENS * 4);
  int*   inv1        = (int*)alloc((size_t)T_TOKENS * 4);
  unsigned short* xb   = (unsigned short*)alloc((size_t)T_TOKENS * H_DIM * 2 + 512);
  unsigned short* w1t  = (unsigned short*)alloc((size_t)E_NUM * F_DIM * H_DIM * 2 + 512);
  unsigned short* hmid = (unsigned short*)alloc((size_t)MAX_PAIRS * F_DIM * 2 + 512);
  // w2t lives in d_out (64MB; w2t needs 32MB); combine overwrites d_out afterward.
  unsigned short* w2t = (unsigned short*)d_out;

  hipFuncSetAttribute((const void*)&moe_gemm8<0, H_DIM, F_DIM, TOT_T>,
                      hipFuncAttributeMaxDynamicSharedMemorySize, 131072);
  hipFuncSetAttribute((const void*)&moe_gemm8<1, F_DIM, H_DIM, TOT_T>,
                      hipFuncAttributeMaxDynamicSharedMemorySize, 131072);

  hipMemsetAsync(meta, 0, 256, stream);
  hipMemsetAsync(pair_token, 0xFF, (size_t)MAX_PAIRS * 4, stream);  // -1

  dim3 b256(256), b512(512);
  // fused prep: router (1024) + W1 transpose (4096) + W2 transpose (4096)
  prep_kernel<<<dim3(9216), b256, 0, stream>>>(x, Wg, W1, W2, xb, w1t, w2t,
                                               topk, counts, scal);
  scan_kernel<<<1, b256, 0, stream>>>(counts, po, tile_expert);
  assign_kernel<<<T_TOKENS / 256, b256, 0, stream>>>(topk, po, cursors, pair_token, pair_w,
                                                     inv0, inv1);
  // GEMM1 (static, 1152 blocks): hmid = gelu(gather(xb) @ W1t^T)
  moe_gemm8<0, H_DIM, F_DIM, TOT_T><<<dim3((F_DIM / 256) * TOT_T), b512, 131072, stream>>>(
      xb, w1t, pair_token, pair_w, tile_expert, 0, hmid);
  // GEMM2 (static, 576 blocks): hmid[p][0:1024) = bf16(w(p)*(hmid[p]@W2t^T)) in-place
  moe_gemm8<1, F_DIM, H_DIM, TOT_T><<<dim3((H_DIM / 256) * TOT_T), b512, 131072, stream>>>(
      hmid, w2t, pair_token, pair_w, tile_expert, 0, hmid);
  // combine + fused finalize (overwrites all of d_out, incl. the w2t scratch)
  combine_kernel<<<dim3(T_TOKENS * 128 / 256), b256, 0, stream>>>(hmid, inv0, inv1, outp, scal);
}